// Round 8
// baseline (426.557 us; speedup 1.0000x reference)
//
#include <hip/hip_runtime.h>

#define NN 50000
#define EE 800000
#define BB 1000
#define NB 196      // ceil(NN/256) scan blocks
#define NR 8        // node ranges for LDS histogram
#define RS 6272     // range size, NR*RS = 50176 >= NN
#define NC 32       // edge chunks / partial copies
#define CHUNK 25000 // EE/NC

#define DEGBLKS (NR * NC)          // 256
#define BUILDBLKS 15625            // NN*160/512
#define PACKBLKS 204               // (15*12*512 + 6*4*512)/512

typedef unsigned short u16;
typedef __attribute__((ext_vector_type(8))) short bf16x8;
typedef __attribute__((ext_vector_type(4))) float f32x4;

static __device__ __forceinline__ u16 f2b(float f) {
    union { float f; unsigned u; } v;
    v.f = f;
    unsigned r = v.u + 0x7fffu + ((v.u >> 16) & 1u);
    return (u16)(r >> 16);
}

static __device__ __forceinline__ float b2f(short s) {
    union { unsigned u; float f; } c;
    c.u = ((unsigned)(u16)s) << 16;
    return c.f;
}

// ---------------- front: degcnt (LDS hist) + build_A + packW, blockIdx-partitioned ----------------
// A k-layout: [xin(0:96)|ph(96:160)|t1x(160:256)|t1h(256:320)|t2x(320:416)|t2h(416:480)]
__global__ __launch_bounds__(512) void k_front(
    const int* __restrict__ src, const int* __restrict__ dst,
    const float* __restrict__ ew, float* __restrict__ deg_p, int* __restrict__ cnt_p,
    const float* __restrict__ z, const float* __restrict__ x,
    const float* __restrict__ ph, u16* __restrict__ A,
    const float* __restrict__ Wxz, const float* __restrict__ Wxr,
    const float* __restrict__ Wxh, const float* __restrict__ Whz,
    const float* __restrict__ Whr, const float* __restrict__ Whh,
    u16* __restrict__ Wp, u16* __restrict__ W3p, int* __restrict__ ctr) {
    __shared__ float sdeg[RS];
    __shared__ int scnt[RS];
    int bid = blockIdx.x;
    if (bid < DEGBLKS) {
        if (bid == 0 && threadIdx.x == 0) atomicExch(ctr, 0);  // barrier counter for k_scan
        int r = bid & (NR - 1);
        int c = bid >> 3;
        int base = r * RS;
        for (int i = threadIdx.x; i < RS; i += 512) {
            sdeg[i] = 0.f;
            scnt[i] = 0;
        }
        __syncthreads();
        int e0 = c * CHUNK;
        for (int j = threadIdx.x; j < CHUNK; j += 512) {
            int e = e0 + j;
            int s = src[e], d = dst[e];
            int sl = s - base, dl = d - base;
            if ((unsigned)sl < RS) atomicAdd(&sdeg[sl], ew[e]);
            if ((unsigned)dl < RS) atomicAdd(&scnt[dl], 1);
        }
        __syncthreads();
        int lim = (NN - base < RS) ? (NN - base) : RS;
        for (int i = threadIdx.x; i < lim; i += 512) {
            deg_p[(size_t)c * NN + base + i] = sdeg[i];
            cnt_p[(size_t)c * NN + base + i] = scnt[i];
        }
    } else if (bid < DEGBLKS + BUILDBLKS) {
        int i = (bid - DEGBLKS) * 512 + threadIdx.x;  // over NN*160 exactly
        int n = i / 160, c = i - n * 160;
        float v;
        if (c < 64) v = z[n * 64 + c];
        else if (c < 96) v = x[n * 32 + (c - 64)];
        else v = ph[n * 64 + (c - 96)];
        A[(size_t)n * 480 + c] = f2b(v);
    } else {
        int idx = (bid - DEGBLKS - BUILDBLKS) * 512 + threadIdx.x;
        if (idx < 15 * 12 * 512) {
            int j = idx & 7, l = (idx >> 3) & 63;
            int ct = (idx >> 9) % 12, s = (idx >> 9) / 12;
            int k = 32 * s + (l >> 4) * 8 + j;
            int g = ct >> 2;
            int c = 16 * (ct & 3) + (l & 15);
            bool isX;
            int kr;
            if (k < 96)       { isX = true;  kr = k; }
            else if (k < 160) { isX = false; kr = k - 96; }
            else if (k < 256) { isX = true;  kr = 96 + (k - 160); }
            else if (k < 320) { isX = false; kr = 64 + (k - 256); }
            else if (k < 416) { isX = true;  kr = 192 + (k - 320); }
            else              { isX = false; kr = 128 + (k - 416); }
            float val;
            if (isX) {
                const float* W = (g == 0) ? Wxz : ((g == 1) ? Wxr : Wxh);
                val = W[kr * 64 + c];
            } else if (g == 2) {
                val = 0.f;
            } else {
                const float* W = (g == 0) ? Whz : Whr;
                val = W[kr * 64 + c];
            }
            Wp[idx] = f2b(val);
        } else {
            int i2 = idx - 15 * 12 * 512;
            int j = i2 & 7, l = (i2 >> 3) & 63;
            int ct = (i2 >> 9) & 3, s = i2 >> 11;
            int k = 32 * s + (l >> 4) * 8 + j;
            int ki = k >> 6, kr = k & 63;
            int c = 16 * ct + (l & 15);
            W3p[i2] = f2b(Whh[(ki * 64 + kr) * 64 + c]);
        }
    }
}

// ---------------- fused scan: reduce partials + block scan + grid barrier + prefix ----------------
__global__ __launch_bounds__(256) void k_scan(
    const int* __restrict__ cnt_p, const float* __restrict__ deg_p,
    int* __restrict__ cnt, int* __restrict__ row_ptr, int* __restrict__ cursor,
    float* __restrict__ dinv, int* __restrict__ bsum, int* __restrict__ ctr) {
    __shared__ int s[256];
    int b = blockIdx.x;
    int i = b * 256 + threadIdx.x;
    int v = 0;
    float d = 0.f;
    if (i < NN) {
#pragma unroll
        for (int p = 0; p < NC; p++) v += cnt_p[(size_t)p * NN + i];
#pragma unroll
        for (int p = 0; p < NC; p++) d += deg_p[(size_t)p * NN + i];
        cnt[i] = v;
    }
    s[threadIdx.x] = v;
    __syncthreads();
    for (int off = 1; off < 256; off <<= 1) {
        int t = (threadIdx.x >= off) ? s[threadIdx.x - off] : 0;
        __syncthreads();
        s[threadIdx.x] += t;
        __syncthreads();
    }
    int incl = s[threadIdx.x];
    if (threadIdx.x == 255) atomicExch(&bsum[b], s[255]);  // device-scope publish
    __threadfence();
    // grid barrier (NB=196 blocks <= 256 CUs -> co-resident)
    if (threadIdx.x == 0) {
        atomicAdd(ctr, 1);
        while (atomicAdd(ctr, 0) < NB) __builtin_amdgcn_s_sleep(8);
    }
    __syncthreads();
    __threadfence();
    // prefix over preceding block sums (b <= 195 < 256: one read per thread)
    int pv = (threadIdx.x < b) ? atomicAdd(&bsum[threadIdx.x], 0) : 0;
    s[threadIdx.x] = pv;
    __syncthreads();
    for (int off = 128; off > 0; off >>= 1) {
        if (threadIdx.x < off) s[threadIdx.x] += s[threadIdx.x + off];
        __syncthreads();
    }
    int prefix = s[0];
    if (i < NN) {
        int start = prefix + incl - v;
        row_ptr[i] = start;
        cursor[i] = start;
        dinv[i] = d > 0.f ? rsqrtf(d) : 0.f;
    }
}

// ---------------- scatter: 8B records {src, w} ----------------
__global__ void k_scatter(const int* __restrict__ src, const int* __restrict__ dst,
                          const float* __restrict__ ew, const float* __restrict__ dinv,
                          int* __restrict__ cursor, uint2* __restrict__ csr8) {
    int e = blockIdx.x * 256 + threadIdx.x;
    if (e >= EE) return;
    int d = dst[e], s = src[e];
    int pos = atomicAdd(&cursor[d], 1);
    float w = dinv[s] * ew[e] * dinv[d];
    csr8[pos] = make_uint2((unsigned)s, __float_as_uint(w));
}

// ---------------- bf16 pull propagation, 16 ch/thread ----------------
template <int C, int SCALE, bool HB, int BS, int OS>
__global__ __launch_bounds__(BS) void k_pull(
    const u16* __restrict__ Abase, int inofs, int baseofs, int outofs,
    const uint2* __restrict__ csr8, const int* __restrict__ row_ptr,
    const int* __restrict__ cnt) {
    constexpr int TPR = C / 16;
    int tid = blockIdx.x * BS + threadIdx.x;
    int r = tid / TPR;
    int c16 = (tid - r * TPR) * 16;
    if (r >= NN) return;
    int s0 = row_ptr[r], n = cnt[r];
    float acc[16];
#pragma unroll
    for (int k = 0; k < 16; k++) acc[k] = 0.f;
    const u16* in = Abase + inofs + c16;
    uint2 e = (n > 0) ? csr8[s0] : make_uint2(0u, 0u);
    for (int j = 0; j < n; j++) {
        uint2 ec = e;
        if (j + 1 < n) e = csr8[s0 + j + 1];
        float w = __uint_as_float(ec.y);
        const u16* p = in + (size_t)ec.x * OS;
        bf16x8 v0 = *(const bf16x8*)(p);
        bf16x8 v1 = *(const bf16x8*)(p + 8);
#pragma unroll
        for (int k = 0; k < 8; k++) {
            acc[k] += w * b2f(v0[k]);
            acc[8 + k] += w * b2f(v1[k]);
        }
    }
    const float sc = -(float)SCALE;
    float o[16];
    if (HB) {
        const u16* bp = Abase + (size_t)r * OS + baseofs + c16;
        bf16x8 b0 = *(const bf16x8*)(bp);
        bf16x8 b1 = *(const bf16x8*)(bp + 8);
#pragma unroll
        for (int k = 0; k < 8; k++) {
            o[k] = sc * acc[k] - b2f(b0[k]);
            o[8 + k] = sc * acc[8 + k] - b2f(b1[k]);
        }
    } else {
#pragma unroll
        for (int k = 0; k < 16; k++) o[k] = sc * acc[k];
    }
    bf16x8 p0, p1;
#pragma unroll
    for (int k = 0; k < 8; k++) {
        p0[k] = (short)f2b(o[k]);
        p1[k] = (short)f2b(o[8 + k]);
    }
    u16* op = const_cast<u16*>(Abase) + (size_t)r * OS + outofs + c16;
    *(bf16x8*)(op) = p0;
    *(bf16x8*)(op + 8) = p1;
}

// ---------------- gates GEMM (MFMA): [N,480]x[480,192] -> Zb16, Hx16, A3 slice ----------------
__global__ __launch_bounds__(256) void k_gates_mfma(
    const u16* __restrict__ A, const u16* __restrict__ Wp,
    const float* __restrict__ bxz, const float* __restrict__ bhz,
    const float* __restrict__ bxr, const float* __restrict__ bhr,
    const float* __restrict__ bxh,
    u16* __restrict__ Zb16, u16* __restrict__ Hx16, u16* __restrict__ A3) {
    int wv = (blockIdx.x * 256 + threadIdx.x) >> 6;
    int lane = threadIdx.x & 63;
    int r0 = wv * 16;
    if (r0 >= NN) return;
    int q = lane >> 4, j0 = lane & 15;

    f32x4 acc[12];
#pragma unroll
    for (int i = 0; i < 12; i++) acc[i] = (f32x4){0.f, 0.f, 0.f, 0.f};

    const u16* arow = A + (size_t)(r0 + j0) * 480 + q * 8;
#pragma unroll
    for (int s = 0; s < 15; s++) {
        bf16x8 a = *(const bf16x8*)(arow + 32 * s);
        const u16* bp = Wp + (size_t)(s * 12) * 512 + lane * 8;
#pragma unroll
        for (int ct = 0; ct < 12; ct++) {
            bf16x8 b = *(const bf16x8*)(bp + ct * 512);
            acc[ct] = __builtin_amdgcn_mfma_f32_16x16x32_bf16(a, b, acc[ct], 0, 0, 0);
        }
    }

#pragma unroll
    for (int ct = 0; ct < 4; ct++) {
        int j = 16 * ct + j0;
        float bz = bxz[j] + bhz[j];
        float br = bxr[j] + bhr[j];
        float bh = bxh[j];
#pragma unroll
        for (int reg = 0; reg < 4; reg++) {
            int r = r0 + q * 4 + reg;
            size_t i = (size_t)r * 64 + j;
            float zp = acc[ct][reg] + bz;
            float rp = acc[ct + 4][reg] + br;
            float hp = acc[ct + 8][reg] + bh;
            float zv = 1.f / (1.f + expf(-zp));
            float rv = 1.f / (1.f + expf(-rp));
            float phv = b2f((short)A[(size_t)r * 480 + 96 + j]);
            Zb16[i] = f2b(zv);
            Hx16[i] = f2b(hp);
            A3[(size_t)r * 192 + j] = f2b(rv * phv);
        }
    }
}

// ---------------- final GEMM + GRU blend, fused with batch tail ----------------
#define FINBLKS 782  // ceil(3125 waves / 4)
__global__ __launch_bounds__(256) void k_final_tail(
    const u16* __restrict__ A3, const u16* __restrict__ W3p,
    const float* __restrict__ bhh, const u16* __restrict__ Hx16,
    const u16* __restrict__ Zb16, const u16* __restrict__ A,
    float* __restrict__ outh,
    const float* __restrict__ z, const int* __restrict__ batch,
    const float* __restrict__ u, const float* __restrict__ Wg,
    const float* __restrict__ bg, float* __restrict__ outF) {
    if (blockIdx.x >= FINBLKS) {
        // ---- tail: graph emb (binary search over sorted batch) + global emb ----
        int b = ((blockIdx.x - FINBLKS) * 256 + threadIdx.x) >> 6;
        int lane = threadIdx.x & 63;
        if (b >= BB) return;
        int lo = 0, hi = NN;
        while (lo < hi) {
            int m = (lo + hi) >> 1;
            if (batch[m] < b) lo = m + 1; else hi = m;
        }
        int start = lo;
        hi = NN;
        while (lo < hi) {
            int m = (lo + hi) >> 1;
            if (batch[m] < b + 1) lo = m + 1; else hi = m;
        }
        int end = lo;
        float acc = 0.f;
        for (int n = start; n < end; n++) acc += z[(size_t)n * 64 + lane];
        float g = bg[lane];
        const float* ur = u + (size_t)b * 64;
        for (int k = 0; k < 64; k++) g += ur[k] * Wg[k * 64 + lane];
        g = fmaxf(g, 0.f);
        outF[(size_t)b * 128 + lane] = acc;
        outF[(size_t)b * 128 + 64 + lane] = g;
        return;
    }
    int wv = (blockIdx.x * 256 + threadIdx.x) >> 6;
    int lane = threadIdx.x & 63;
    int r0 = wv * 16;
    if (r0 >= NN) return;
    int q = lane >> 4, j0 = lane & 15;

    f32x4 acc[4];
#pragma unroll
    for (int i = 0; i < 4; i++) acc[i] = (f32x4){0.f, 0.f, 0.f, 0.f};

    const u16* arow = A3 + (size_t)(r0 + j0) * 192 + q * 8;
#pragma unroll
    for (int s = 0; s < 6; s++) {
        bf16x8 a = *(const bf16x8*)(arow + 32 * s);
        const u16* bp = W3p + (size_t)(s * 4) * 512 + lane * 8;
#pragma unroll
        for (int ct = 0; ct < 4; ct++) {
            bf16x8 b = *(const bf16x8*)(bp + ct * 512);
            acc[ct] = __builtin_amdgcn_mfma_f32_16x16x32_bf16(a, b, acc[ct], 0, 0, 0);
        }
    }

#pragma unroll
    for (int ct = 0; ct < 4; ct++) {
        int j = 16 * ct + j0;
        float bh = bhh[j];
#pragma unroll
        for (int reg = 0; reg < 4; reg++) {
            int r = r0 + q * 4 + reg;
            size_t i = (size_t)r * 64 + j;
            float ht = tanhf(b2f((short)Hx16[i]) + acc[ct][reg] + bh);
            float zv = b2f((short)Zb16[i]);
            float phv = b2f((short)A[(size_t)r * 480 + 96 + j]);
            outh[i] = zv * phv + (1.f - zv) * ht;
        }
    }
}

extern "C" void kernel_launch(void* const* d_in, const int* in_sizes, int n_in,
                              void* d_out, int out_size, void* d_ws, size_t ws_size,
                              hipStream_t stream) {
    const float* x  = (const float*)d_in[0];
    const float* u  = (const float*)d_in[1];
    const float* z  = (const float*)d_in[2];
    const int*   ei = (const int*)d_in[3];
    const float* ew = (const float*)d_in[4];
    const int* batch = (const int*)d_in[5];
    const float* ph = (const float*)d_in[7];
    const float *Wxz = (const float*)d_in[8],  *bxz = (const float*)d_in[9];
    const float *Whz = (const float*)d_in[10], *bhz = (const float*)d_in[11];
    const float *Wxr = (const float*)d_in[12], *bxr = (const float*)d_in[13];
    const float *Whr = (const float*)d_in[14], *bhr = (const float*)d_in[15];
    const float *Wxh = (const float*)d_in[16], *bxh = (const float*)d_in[17];
    const float *Whh = (const float*)d_in[18], *bhh = (const float*)d_in[19];
    const float *Wg  = (const float*)d_in[20], *bg  = (const float*)d_in[21];
    const int* src = ei;
    const int* dst = ei + EE;

    char* wsb = (char*)d_ws;
    size_t o = 0;
    auto alloc = [&](size_t bytes) {
        void* p = wsb + o;
        o += (bytes + 255) & ~(size_t)255;
        return p;
    };
    float* deg_p   = (float*)alloc((size_t)NC * NN * 4);  // fully overwritten
    int*   cnt_p   = (int*)alloc((size_t)NC * NN * 4);    // fully overwritten
    int*   cnt     = (int*)alloc(NN * 4);
    int*   row_ptr = (int*)alloc(NN * 4);
    int*   cursor  = (int*)alloc(NN * 4);
    float* dinv    = (float*)alloc(NN * 4);
    int*   bsum    = (int*)alloc(256 * 4);
    int*   ctr     = (int*)alloc(256);
    uint2* csr8    = (uint2*)alloc((size_t)EE * 8);
    u16*   Zb16 = (u16*)alloc((size_t)NN * 64 * 2);
    u16*   Hx16 = (u16*)alloc((size_t)NN * 64 * 2);
    u16*   A    = (u16*)alloc((size_t)NN * 480 * 2);
    u16*   A3   = (u16*)alloc((size_t)NN * 192 * 2);
    u16*   Wp   = (u16*)alloc(15 * 12 * 512 * 2);
    u16*   W3p  = (u16*)alloc(6 * 4 * 512 * 2);

    float* outF = (float*)d_out;               // [B,128]
    float* outH = outF + (size_t)BB * 128;     // [N,64]

    const int BLK = 256;
    const int gE = (EE + BLK - 1) / BLK;
    const int gPull160 = (NN + 31) / 32;  // 320 thr, 10 thr/row (16ch) -> 32 rows/blk
    const int gPull64 = (NN + 63) / 64;   // 256 thr, 4 thr/row (16ch) -> 64 rows/blk
    const int gMFMA = FINBLKS;
    const int gTail = (BB * 64 + BLK - 1) / BLK;  // 250

    // 1. front: degcnt LDS hist + build A + pack weights + zero barrier ctr
    k_front<<<DEGBLKS + BUILDBLKS + PACKBLKS, 512, 0, stream>>>(
        src, dst, ew, deg_p, cnt_p, z, x, ph, A,
        Wxz, Wxr, Wxh, Whz, Whr, Whh, Wp, W3p, ctr);

    // 2. fused scan (reduce partials, prefix via in-kernel grid barrier, dinv)
    k_scan<<<NB, 256, 0, stream>>>(cnt_p, deg_p, cnt, row_ptr, cursor, dinv, bsum, ctr);

    // 3. scatter 8B CSR records
    k_scatter<<<gE, BLK, 0, stream>>>(src, dst, ew, dinv, cursor, csr8);

    // 4. Chebyshev bases, merged 160-ch pulls: t1 = -prop(t0); t2 = -2*prop(t1) - t0
    k_pull<160, 1, false, 320, 480><<<gPull160, 320, 0, stream>>>(A, 0, 0, 160, csr8, row_ptr, cnt);
    k_pull<160, 2, true, 320, 480><<<gPull160, 320, 0, stream>>>(A, 160, 0, 320, csr8, row_ptr, cnt);

    // 5. gates GEMM -> Zb16, Hx16, A3 slice 0 (hr)
    k_gates_mfma<<<gMFMA, BLK, 0, stream>>>(A, Wp, bxz, bhz, bxr, bhr, bxh, Zb16, Hx16, A3);

    // 6. Chebyshev basis for hr (in A3)
    k_pull<64, 1, false, 256, 192><<<gPull64, 256, 0, stream>>>(A3, 0, 0, 64, csr8, row_ptr, cnt);
    k_pull<64, 2, true, 256, 192><<<gPull64, 256, 0, stream>>>(A3, 64, 0, 128, csr8, row_ptr, cnt);

    // 7. candidate GEMM + GRU blend -> h out; extra blocks do batch tail -> fused out
    k_final_tail<<<gMFMA + gTail, BLK, 0, stream>>>(A3, W3p, bhh, Hx16, Zb16, A, outH,
                                                    z, batch, u, Wg, bg, outF);
}